// Round 4
// baseline (319.504 us; speedup 1.0000x reference)
//
#include <hip/hip_runtime.h>
#include <math.h>

#define F_EPS 1e-15f
#define F_BALL 0.99999f              /* 1 - BALL_EPS */
#define F_TANH_ARG_MAX 15.0f
#define F_ATANH_MAX (1.0f - 1e-7f)
#define F_LOG2E 1.4426950408889634f
#define F_LN2   0.6931471805599453f

// ---- fast hardware math ----
__device__ __forceinline__ float rcp_fast(float x) {
    float r = __builtin_amdgcn_rcpf(x);
    return r * (2.0f - x * r);                  // 1 Newton step -> ~fp32 accurate
}
__device__ __forceinline__ float sqrt_fast(float x) { return __builtin_amdgcn_sqrtf(x); }
__device__ __forceinline__ float exp2_fast(float x) { return __builtin_amdgcn_exp2f(x); }
__device__ __forceinline__ float log2_fast(float x) { return __builtin_amdgcn_logf(x); }
__device__ __forceinline__ float exp_fast(float x)  { return exp2_fast(x * F_LOG2E); }

__device__ __forceinline__ float tanh_fast(float x) {
    float ax = fabsf(x);
    float t  = exp2_fast(ax * (-2.0f * F_LOG2E));     // e^{-2|x|}
    float r  = (1.0f - t) * rcp_fast(1.0f + t);
    return copysignf(r, x);
}
__device__ __forceinline__ float atanh_fast(float z) {   // z in [0, 1)
    return (0.5f * F_LN2) * log2_fast((1.0f + z) * rcp_fast(1.0f - z));
}
__device__ __forceinline__ float softplus_fast(float x) {
    return F_LN2 * log2_fast(1.0f + exp2_fast(x * F_LOG2E));
}

// ---- scalar chain pieces, norm-carrying (per-lane, one row per lane&3) ----
struct GramS { float X2, Y2, XY; };

__device__ __forceinline__ float gnorm2(const GramS& g, float a, float b) {
    return fmaxf(a * a * g.X2 + 2.0f * a * b * g.XY + b * b * g.Y2, 0.0f);
}
__device__ __forceinline__ float gdot(const GramS& g, float au, float bu, float av, float bv) {
    return au * av * g.X2 + (au * bv + bu * av) * g.XY + bu * bv * g.Y2;
}

__device__ __forceinline__ void madd_c(float c, float u2, float v2, float uv,
                                       float au, float bu, float av, float bv,
                                       float& ao, float& bo) {
    float twocuv = 2.0f * c * uv;
    float A = 1.0f + twocuv + c * v2;
    float B = 1.0f - c * u2;
    float rden = rcp_fast(fmaxf(1.0f + twocuv + c * c * u2 * v2, F_EPS));
    ao = (A * au + B * av) * rden;
    bo = (A * bu + B * bv) * rden;
}

__device__ __forceinline__ float pclip(const GramS& g, float maxn_post, float& a, float& b) {
    float n = fmaxf(sqrt_fast(gnorm2(g, a, b)), F_EPS);
    float s = fminf(1.0f, maxn_post * rcp_fast(n));
    a *= s; b *= s;
    return s * n;                       // == min(n, maxn_post)
}

__device__ __forceinline__ float msm_coef(float sc, float rcp_sc, float r,
                                          float n_in, float& n_out) {
    float ne = fmaxf(n_in, F_EPS);
    float z  = fminf(sc * ne, F_ATANH_MAX);
    float w  = tanh_fast(r * atanh_fast(z));
    float m  = w * rcp_fast(sc * ne);
    float aw = fabsf(w);
    float s  = fminf(1.0f, F_BALL * rcp_fast(fmaxf(aw, F_EPS)));   // post_clip
    n_out = s * aw * rcp_sc;
    return m * s;
}

__device__ __forceinline__ float hr_c(float nx, float sc, float rcp_sc,
                                      float maxn_pre, float& n_out) {
    float s1 = fminf(1.0f, maxn_pre * rcp_fast(nx));    // pre_clip (nx >= EPS)
    float n1 = fmaxf(s1 * nx, F_EPS);
    float t  = tanh_fast(sc * n1);                      // >= 0
    float f1 = t * rcp_fast(sc * n1);                   // expmap0 coef
    float s2 = fminf(1.0f, F_BALL * rcp_fast(fmaxf(t, F_EPS)));  // post_clip
    n_out = s2 * t * rcp_sc;
    return s1 * f1 * s2;
}

// Computes (fa, fb) for 4 rows handled by this wave; lane r (r = lane&3) owns
// row row0+r. Returns via reference; caller decides what to do with them.
__device__ __forceinline__ void chain_4rows(
    float gX2, float gY2, float gXY,
    float curv, float graw, float gscale, float scent,
    float& fa, float& fb)
{
    GramS g; g.X2 = gX2; g.Y2 = gY2; g.XY = gXY;

    const float c      = softplus_fast(curv);
    const float sc     = sqrt_fast(c);
    const float rcp_sc = rcp_fast(sc);
    const float maxn_pre  = F_TANH_ARG_MAX * rcp_sc;
    const float maxn_post = F_BALL * rcp_sc;
    const float s      = rcp_fast(1.0f + exp_fast(-scent));      // sigmoid
    const float g_max  = 1.0f + softplus_fast(gscale);
    const float gamma  = g_max * tanh_fast(graw);

    const float nx = fmaxf(sqrt_fast(gX2), F_EPS);
    const float ny = fmaxf(sqrt_fast(gY2), F_EPS);

    float n_hx, n_hy;
    const float hx = hr_c(nx, sc, rcp_sc, maxn_pre, n_hx);       // hr_x = hx * x
    const float hy = hr_c(ny, sc, rcp_sc, maxn_pre, n_hy);       // hr_y = hy * y

    float n_sx, n_sy;
    const float sxa = hx * msm_coef(sc, rcp_sc, s,        n_hx, n_sx);
    const float syb = hy * msm_coef(sc, rcp_sc, 1.0f - s, n_hy, n_sy);

    float pa, pb;
    {
        float u2 = n_sx * n_sx, v2 = n_sy * n_sy;
        float uv = sxa * syb * gXY;
        madd_c(c, u2, v2, uv, sxa, 0.0f, 0.0f, syb, pa, pb);
    }
    const float n_p = pclip(g, maxn_post, pa, pb);
    const float np2 = n_p * n_p;

    float xpa, xpb;
    {
        float v2 = n_hx * n_hx;
        float uv = -hx * (pa * gX2 + pb * gXY);
        madd_c(c, np2, v2, uv, -pa, -pb, hx, 0.0f, xpa, xpb);
    }
    const float n_xp = pclip(g, maxn_post, xpa, xpb);

    float ypa, ypb;
    {
        float v2 = n_hy * n_hy;
        float uv = -hy * (pa * gXY + pb * gY2);
        madd_c(c, np2, v2, uv, -pa, -pb, 0.0f, hy, ypa, ypb);
    }
    float n_yp = pclip(g, maxn_post, ypa, ypb);

    float n_ys;
    {
        float m = msm_coef(sc, rcp_sc, gamma, n_yp, n_ys);
        ypa *= m; ypb *= m;
    }

    float ha, hb;
    {
        float u2 = n_xp * n_xp, v2 = n_ys * n_ys;
        float uv = gdot(g, xpa, xpb, ypa, ypb);
        madd_c(c, u2, v2, uv, xpa, xpb, ypa, ypb, ha, hb);
    }
    const float n_h = pclip(g, maxn_post, ha, hb);

    float ra, rb;
    {
        float u2 = np2, v2 = n_h * n_h;
        float uv = gdot(g, pa, pb, ha, hb);
        madd_c(c, u2, v2, uv, pa, pb, ha, hb, ra, rb);
    }
    const float n_r = pclip(g, maxn_post, ra, rb);

    const float nrr = fmaxf(n_r, F_EPS);
    const float z   = fminf(sc * nrr, F_ATANH_MAX);
    const float f   = atanh_fast(z) * rcp_fast(sc * nrr);
    fa = f * ra;
    fb = f * rb;
}

// ---------------- K1: gram + chain -> (fa, fb) per row in d_ws --------------
// Pure-read streaming kernel: 227 MB in, 295 KB out. Also warms L3 for K2.
__global__ __launch_bounds__(256) void hra_gram(
    const float* __restrict__ x, const float* __restrict__ y,
    const float* __restrict__ p_curv, const float* __restrict__ p_graw,
    const float* __restrict__ p_gscale, const float* __restrict__ p_scent,
    float2* __restrict__ fab, int rows)
{
    const int wid  = (blockIdx.x << 2) | (threadIdx.x >> 6);
    const int lane = threadIdx.x & 63;
    const int row0 = wid << 2;                                 // 4 rows per wave
    if (row0 >= rows) return;

    const float curv   = p_curv[0];
    const float graw   = p_graw[0];
    const float gscale = p_gscale[0];
    const float scent  = p_scent[0];

    int ridx[4];
#pragma unroll
    for (int r = 0; r < 4; ++r) ridx[r] = min(row0 + r, rows - 1);

    float4 xv[4][3], yv[4][3];
#pragma unroll
    for (int r = 0; r < 4; ++r) {
        const float4* xr = (const float4*)(x + (size_t)ridx[r] * 768);
        const float4* yr = (const float4*)(y + (size_t)ridx[r] * 768);
#pragma unroll
        for (int j = 0; j < 3; ++j) {
            xv[r][j] = xr[lane + 64 * j];
            yv[r][j] = yr[lane + 64 * j];
        }
    }

    float X2[4], Y2[4], XY[4];
#pragma unroll
    for (int r = 0; r < 4; ++r) {
        float sxx = 0.0f, syy = 0.0f, sxy = 0.0f;
#pragma unroll
        for (int j = 0; j < 3; ++j) {
            sxx += xv[r][j].x * xv[r][j].x + xv[r][j].y * xv[r][j].y
                 + xv[r][j].z * xv[r][j].z + xv[r][j].w * xv[r][j].w;
            syy += yv[r][j].x * yv[r][j].x + yv[r][j].y * yv[r][j].y
                 + yv[r][j].z * yv[r][j].z + yv[r][j].w * yv[r][j].w;
            sxy += xv[r][j].x * yv[r][j].x + xv[r][j].y * yv[r][j].y
                 + xv[r][j].z * yv[r][j].z + xv[r][j].w * yv[r][j].w;
        }
        X2[r] = sxx; Y2[r] = syy; XY[r] = sxy;
    }

#pragma unroll
    for (int o = 32; o > 0; o >>= 1) {
#pragma unroll
        for (int r = 0; r < 4; ++r) {
            X2[r] += __shfl_xor(X2[r], o, 64);
            Y2[r] += __shfl_xor(Y2[r], o, 64);
            XY[r] += __shfl_xor(XY[r], o, 64);
        }
    }

    const int rsel = lane & 3;
    const float gX2 = rsel == 0 ? X2[0] : rsel == 1 ? X2[1] : rsel == 2 ? X2[2] : X2[3];
    const float gY2 = rsel == 0 ? Y2[0] : rsel == 1 ? Y2[1] : rsel == 2 ? Y2[2] : Y2[3];
    const float gXY = rsel == 0 ? XY[0] : rsel == 1 ? XY[1] : rsel == 2 ? XY[2] : XY[3];

    float fa, fb;
    chain_4rows(gX2, gY2, gXY, curv, graw, gscale, scent, fa, fb);

    // lanes 0..3 hold (fa,fb) for rows row0+0..3
    if (lane < 4 && row0 + lane < rows) {
        float2 v; v.x = fa; v.y = fb;
        fab[row0 + lane] = v;
    }
}

// ---------------- K2: out = fa[row]*x + fb[row]*y (pure blend stream) -------
__global__ __launch_bounds__(256) void hra_blend(
    const float4* __restrict__ x4, const float4* __restrict__ y4,
    const float2* __restrict__ fab, float4* __restrict__ out4, int n4)
{
    int i = blockIdx.x * 256 + threadIdx.x;
    const int stride = gridDim.x * 256;
    for (; i < n4; i += stride) {
        const int row = i / 192;            // 192 float4 per 768-float row
        const float2 s = fab[row];
        const float4 a = x4[i];
        const float4 b = y4[i];
        float4 o;
        o.x = s.x * a.x + s.y * b.x;
        o.y = s.x * a.y + s.y * b.y;
        o.z = s.x * a.z + s.y * b.z;
        o.w = s.x * a.w + s.y * b.w;
        out4[i] = o;
    }
}

// ---------------- fallback: proven single-kernel version (R2) ---------------
__global__ __launch_bounds__(256) void hra_kernel(
    const float* __restrict__ x, const float* __restrict__ y,
    const float* __restrict__ p_curv, const float* __restrict__ p_graw,
    const float* __restrict__ p_gscale, const float* __restrict__ p_scent,
    float* __restrict__ out, int rows)
{
    const int wid  = (blockIdx.x << 2) | (threadIdx.x >> 6);
    const int lane = threadIdx.x & 63;
    const int row0 = wid << 2;
    if (row0 >= rows) return;

    const float curv   = p_curv[0];
    const float graw   = p_graw[0];
    const float gscale = p_gscale[0];
    const float scent  = p_scent[0];

    int ridx[4];
#pragma unroll
    for (int r = 0; r < 4; ++r) ridx[r] = min(row0 + r, rows - 1);

    float4 xv[4][3], yv[4][3];
#pragma unroll
    for (int r = 0; r < 4; ++r) {
        const float4* xr = (const float4*)(x + (size_t)ridx[r] * 768);
        const float4* yr = (const float4*)(y + (size_t)ridx[r] * 768);
#pragma unroll
        for (int j = 0; j < 3; ++j) {
            xv[r][j] = xr[lane + 64 * j];
            yv[r][j] = yr[lane + 64 * j];
        }
    }

    float X2[4], Y2[4], XY[4];
#pragma unroll
    for (int r = 0; r < 4; ++r) {
        float sxx = 0.0f, syy = 0.0f, sxy = 0.0f;
#pragma unroll
        for (int j = 0; j < 3; ++j) {
            sxx += xv[r][j].x * xv[r][j].x + xv[r][j].y * xv[r][j].y
                 + xv[r][j].z * xv[r][j].z + xv[r][j].w * xv[r][j].w;
            syy += yv[r][j].x * yv[r][j].x + yv[r][j].y * yv[r][j].y
                 + yv[r][j].z * yv[r][j].z + yv[r][j].w * yv[r][j].w;
            sxy += xv[r][j].x * yv[r][j].x + xv[r][j].y * yv[r][j].y
                 + xv[r][j].z * yv[r][j].z + xv[r][j].w * yv[r][j].w;
        }
        X2[r] = sxx; Y2[r] = syy; XY[r] = sxy;
    }

#pragma unroll
    for (int o = 32; o > 0; o >>= 1) {
#pragma unroll
        for (int r = 0; r < 4; ++r) {
            X2[r] += __shfl_xor(X2[r], o, 64);
            Y2[r] += __shfl_xor(Y2[r], o, 64);
            XY[r] += __shfl_xor(XY[r], o, 64);
        }
    }

    const int rsel = lane & 3;
    const float gX2 = rsel == 0 ? X2[0] : rsel == 1 ? X2[1] : rsel == 2 ? X2[2] : X2[3];
    const float gY2 = rsel == 0 ? Y2[0] : rsel == 1 ? Y2[1] : rsel == 2 ? Y2[2] : Y2[3];
    const float gXY = rsel == 0 ? XY[0] : rsel == 1 ? XY[1] : rsel == 2 ? XY[2] : XY[3];

    float fa, fb;
    chain_4rows(gX2, gY2, gXY, curv, graw, gscale, scent, fa, fb);

#pragma unroll
    for (int r = 0; r < 4; ++r) {
        const float far = __shfl(fa, r, 64);
        const float fbr = __shfl(fb, r, 64);
        if (row0 + r < rows) {
            float4* outr = (float4*)(out + (size_t)(row0 + r) * 768);
#pragma unroll
            for (int j = 0; j < 3; ++j) {
                float4 o;
                o.x = far * xv[r][j].x + fbr * yv[r][j].x;
                o.y = far * xv[r][j].y + fbr * yv[r][j].y;
                o.z = far * xv[r][j].z + fbr * yv[r][j].z;
                o.w = far * xv[r][j].w + fbr * yv[r][j].w;
                outr[lane + 64 * j] = o;
            }
        }
    }
}

extern "C" void kernel_launch(void* const* d_in, const int* in_sizes, int n_in,
                              void* d_out, int out_size, void* d_ws, size_t ws_size,
                              hipStream_t stream) {
    const float* x = (const float*)d_in[0];
    const float* y = (const float*)d_in[1];
    const float* curv = (const float*)d_in[2];
    const float* graw = (const float*)d_in[3];
    const float* gscale = (const float*)d_in[4];
    const float* scent = (const float*)d_in[5];
    float* out = (float*)d_out;

    const int rows = in_sizes[0] / 768;          // 64*577 = 36928
    const size_t ws_needed = (size_t)rows * sizeof(float2);

    if (d_ws != nullptr && ws_size >= ws_needed) {
        // K1: gram + scalar chain -> (fa, fb) per row (pure-read stream)
        const int blocks1 = (rows + 15) / 16;    // 4 waves/block * 4 rows/wave
        hipLaunchKernelGGL(hra_gram, dim3(blocks1), dim3(256), 0, stream,
                           x, y, curv, graw, gscale, scent,
                           (float2*)d_ws, rows);
        // K2: blend (read stream from L3 + write stream to HBM)
        const int n4 = rows * 192;               // float4 elements
        hipLaunchKernelGGL(hra_blend, dim3(2048), dim3(256), 0, stream,
                           (const float4*)x, (const float4*)y,
                           (const float2*)d_ws, (float4*)out, n4);
    } else {
        // fallback: proven single-kernel path
        const int blocks = (rows + 15) / 16;
        hipLaunchKernelGGL(hra_kernel, dim3(blocks), dim3(256), 0, stream,
                           x, y, curv, graw, gscale, scent, out, rows);
    }
}

// Round 5
// 278.933 us; speedup vs baseline: 1.1455x; 1.1455x over previous
//
#include <hip/hip_runtime.h>
#include <math.h>

#define F_EPS 1e-15f
#define F_BALL 0.99999f              /* 1 - BALL_EPS */
#define F_TANH_ARG_MAX 15.0f
#define F_ATANH_MAX (1.0f - 1e-7f)
#define F_LOG2E 1.4426950408889634f
#define F_LN2   0.6931471805599453f

// ---- fast hardware math ----
__device__ __forceinline__ float rcp_fast(float x) {
    float r = __builtin_amdgcn_rcpf(x);
    return r * (2.0f - x * r);                  // 1 Newton step -> ~fp32 accurate
}
__device__ __forceinline__ float sqrt_fast(float x) { return __builtin_amdgcn_sqrtf(x); }
__device__ __forceinline__ float exp2_fast(float x) { return __builtin_amdgcn_exp2f(x); }
__device__ __forceinline__ float log2_fast(float x) { return __builtin_amdgcn_logf(x); }
__device__ __forceinline__ float exp_fast(float x)  { return exp2_fast(x * F_LOG2E); }

__device__ __forceinline__ float tanh_fast(float x) {
    float ax = fabsf(x);
    float t  = exp2_fast(ax * (-2.0f * F_LOG2E));     // e^{-2|x|}
    float r  = (1.0f - t) * rcp_fast(1.0f + t);
    return copysignf(r, x);
}
__device__ __forceinline__ float atanh_fast(float z) {   // z in [0, 1)
    return (0.5f * F_LN2) * log2_fast((1.0f + z) * rcp_fast(1.0f - z));
}
__device__ __forceinline__ float softplus_fast(float x) {
    return F_LN2 * log2_fast(1.0f + exp2_fast(x * F_LOG2E));
}

// ---- scalar chain pieces, norm-carrying ----
struct GramS { float X2, Y2, XY; };
struct ChainP { float c, sc, rcp_sc, maxn_pre, maxn_post, s, gamma; };

__device__ __forceinline__ float gnorm2(const GramS& g, float a, float b) {
    return fmaxf(a * a * g.X2 + 2.0f * a * b * g.XY + b * b * g.Y2, 0.0f);
}
__device__ __forceinline__ float gdot(const GramS& g, float au, float bu, float av, float bv) {
    return au * av * g.X2 + (au * bv + bu * av) * g.XY + bu * bv * g.Y2;
}

__device__ __forceinline__ void madd_c(float c, float u2, float v2, float uv,
                                       float au, float bu, float av, float bv,
                                       float& ao, float& bo) {
    float twocuv = 2.0f * c * uv;
    float A = 1.0f + twocuv + c * v2;
    float B = 1.0f - c * u2;
    float rden = rcp_fast(fmaxf(1.0f + twocuv + c * c * u2 * v2, F_EPS));
    ao = (A * au + B * av) * rden;
    bo = (A * bu + B * bv) * rden;
}

__device__ __forceinline__ float pclip(const GramS& g, float maxn_post, float& a, float& b) {
    float n = fmaxf(sqrt_fast(gnorm2(g, a, b)), F_EPS);
    float s = fminf(1.0f, maxn_post * rcp_fast(n));
    a *= s; b *= s;
    return s * n;                       // == min(n, maxn_post)
}

__device__ __forceinline__ float msm_coef(float sc, float rcp_sc, float r,
                                          float n_in, float& n_out) {
    float ne = fmaxf(n_in, F_EPS);
    float z  = fminf(sc * ne, F_ATANH_MAX);
    float w  = tanh_fast(r * atanh_fast(z));
    float m  = w * rcp_fast(sc * ne);
    float aw = fabsf(w);
    float s  = fminf(1.0f, F_BALL * rcp_fast(fmaxf(aw, F_EPS)));   // post_clip
    n_out = s * aw * rcp_sc;
    return m * s;
}

__device__ __forceinline__ float hr_c(float nx, float sc, float rcp_sc,
                                      float maxn_pre, float& n_out) {
    float s1 = fminf(1.0f, maxn_pre * rcp_fast(nx));    // pre_clip (nx >= EPS)
    float n1 = fmaxf(s1 * nx, F_EPS);
    float t  = tanh_fast(sc * n1);                      // >= 0
    float f1 = t * rcp_fast(sc * n1);                   // expmap0 coef
    float s2 = fminf(1.0f, F_BALL * rcp_fast(fmaxf(t, F_EPS)));  // post_clip
    n_out = s2 * t * rcp_sc;
    return s1 * f1 * s2;
}

// full per-row scalar chain: Gram -> (fa, fb). Math identical to the
// verified R2 version (absmax 1.95e-3); params hoisted into ChainP.
__device__ __forceinline__ void chain_row(float gX2, float gY2, float gXY,
                                          const ChainP& P, float& fa, float& fb) {
    GramS g; g.X2 = gX2; g.Y2 = gY2; g.XY = gXY;
    const float c = P.c, sc = P.sc, rcp_sc = P.rcp_sc;
    const float maxn_pre = P.maxn_pre, maxn_post = P.maxn_post;

    const float nx = fmaxf(sqrt_fast(gX2), F_EPS);
    const float ny = fmaxf(sqrt_fast(gY2), F_EPS);

    float n_hx, n_hy;
    const float hx = hr_c(nx, sc, rcp_sc, maxn_pre, n_hx);       // hr_x = hx * x
    const float hy = hr_c(ny, sc, rcp_sc, maxn_pre, n_hy);       // hr_y = hy * y

    float n_sx, n_sy;
    const float sxa = hx * msm_coef(sc, rcp_sc, P.s,        n_hx, n_sx);
    const float syb = hy * msm_coef(sc, rcp_sc, 1.0f - P.s, n_hy, n_sy);

    float pa, pb;
    {
        float u2 = n_sx * n_sx, v2 = n_sy * n_sy;
        float uv = sxa * syb * gXY;
        madd_c(c, u2, v2, uv, sxa, 0.0f, 0.0f, syb, pa, pb);
    }
    const float n_p = pclip(g, maxn_post, pa, pb);
    const float np2 = n_p * n_p;

    float xpa, xpb;
    {
        float v2 = n_hx * n_hx;
        float uv = -hx * (pa * gX2 + pb * gXY);
        madd_c(c, np2, v2, uv, -pa, -pb, hx, 0.0f, xpa, xpb);
    }
    const float n_xp = pclip(g, maxn_post, xpa, xpb);

    float ypa, ypb;
    {
        float v2 = n_hy * n_hy;
        float uv = -hy * (pa * gXY + pb * gY2);
        madd_c(c, np2, v2, uv, -pa, -pb, 0.0f, hy, ypa, ypb);
    }
    float n_yp = pclip(g, maxn_post, ypa, ypb);

    float n_ys;
    {
        float m = msm_coef(sc, rcp_sc, P.gamma, n_yp, n_ys);
        ypa *= m; ypb *= m;
    }

    float ha, hb;
    {
        float u2 = n_xp * n_xp, v2 = n_ys * n_ys;
        float uv = gdot(g, xpa, xpb, ypa, ypb);
        madd_c(c, u2, v2, uv, xpa, xpb, ypa, ypb, ha, hb);
    }
    const float n_h = pclip(g, maxn_post, ha, hb);

    float ra, rb;
    {
        float u2 = np2, v2 = n_h * n_h;
        float uv = gdot(g, pa, pb, ha, hb);
        madd_c(c, u2, v2, uv, pa, pb, ha, hb, ra, rb);
    }
    const float n_r = pclip(g, maxn_post, ra, rb);

    const float nrr = fmaxf(n_r, F_EPS);
    const float z   = fminf(sc * nrr, F_ATANH_MAX);
    const float f   = atanh_fast(z) * rcp_fast(sc * nrr);
    fa = f * ra;
    fb = f * rb;
}

// ---- group = 2 rows. load into a register buffer (12+12 dwordx4 in flight) ----
__device__ __forceinline__ void load_group(const float* __restrict__ x,
                                           const float* __restrict__ y,
                                           int g, int rows, int lane,
                                           float4 (&xv)[2][3], float4 (&yv)[2][3]) {
    const int r0 = g << 1;
#pragma unroll
    for (int r = 0; r < 2; ++r) {
        const int rr = min(r0 + r, rows - 1);
        const float4* xr = (const float4*)(x + (size_t)rr * 768);
        const float4* yr = (const float4*)(y + (size_t)rr * 768);
#pragma unroll
        for (int j = 0; j < 3; ++j) {
            xv[r][j] = xr[lane + 64 * j];
            yv[r][j] = yr[lane + 64 * j];
        }
    }
}

// gram + shfl-reduce + lane-parallel chain (lane&1 owns row r) + blend + store
__device__ __forceinline__ void process_group(float4 (&xv)[2][3], float4 (&yv)[2][3],
                                              int g, int rows, int lane,
                                              const ChainP& P,
                                              float* __restrict__ out) {
    float X2[2], Y2[2], XY[2];
#pragma unroll
    for (int r = 0; r < 2; ++r) {
        float sxx = 0.0f, syy = 0.0f, sxy = 0.0f;
#pragma unroll
        for (int j = 0; j < 3; ++j) {
            sxx += xv[r][j].x * xv[r][j].x + xv[r][j].y * xv[r][j].y
                 + xv[r][j].z * xv[r][j].z + xv[r][j].w * xv[r][j].w;
            syy += yv[r][j].x * yv[r][j].x + yv[r][j].y * yv[r][j].y
                 + yv[r][j].z * yv[r][j].z + yv[r][j].w * yv[r][j].w;
            sxy += xv[r][j].x * yv[r][j].x + xv[r][j].y * yv[r][j].y
                 + xv[r][j].z * yv[r][j].z + xv[r][j].w * yv[r][j].w;
        }
        X2[r] = sxx; Y2[r] = syy; XY[r] = sxy;
    }

#pragma unroll
    for (int o = 32; o > 0; o >>= 1) {
#pragma unroll
        for (int r = 0; r < 2; ++r) {
            X2[r] += __shfl_xor(X2[r], o, 64);
            Y2[r] += __shfl_xor(Y2[r], o, 64);
            XY[r] += __shfl_xor(XY[r], o, 64);
        }
    }

    const int rsel = lane & 1;
    const float gX2 = rsel ? X2[1] : X2[0];
    const float gY2 = rsel ? Y2[1] : Y2[0];
    const float gXY = rsel ? XY[1] : XY[0];

    float fa, fb;
    chain_row(gX2, gY2, gXY, P, fa, fb);

    const int r0 = g << 1;
#pragma unroll
    for (int r = 0; r < 2; ++r) {
        const float far = __shfl(fa, r, 64);    // lane r computed row r0+r
        const float fbr = __shfl(fb, r, 64);
        if (r0 + r < rows) {
            float4* outr = (float4*)(out + (size_t)(r0 + r) * 768);
#pragma unroll
            for (int j = 0; j < 3; ++j) {
                float4 o;
                o.x = far * xv[r][j].x + fbr * yv[r][j].x;
                o.y = far * xv[r][j].y + fbr * yv[r][j].y;
                o.z = far * xv[r][j].z + fbr * yv[r][j].z;
                o.w = far * xv[r][j].w + fbr * yv[r][j].w;
                outr[lane + 64 * j] = o;
            }
        }
    }
}

// Persistent grid-stride waves + register double-buffer: loads for group t+1
// are in flight while group t is reduced/chained/blended (counted vmcnt keeps
// the prefetch outstanding). This is the K2-shape that hit ~5.9 TB/s, fused.
__global__ __launch_bounds__(256) void hra_fused(
    const float* __restrict__ x, const float* __restrict__ y,
    const float* __restrict__ p_curv, const float* __restrict__ p_graw,
    const float* __restrict__ p_gscale, const float* __restrict__ p_scent,
    float* __restrict__ out, int rows)
{
    const int lane   = threadIdx.x & 63;
    const int wglob  = (blockIdx.x << 2) | (threadIdx.x >> 6);
    const int nwaves = gridDim.x << 2;
    const int ngroups = (rows + 1) >> 1;
    if (wglob >= ngroups) return;

    // wave-uniform params, derived once
    const float curv   = p_curv[0];
    const float graw   = p_graw[0];
    const float gscale = p_gscale[0];
    const float scent  = p_scent[0];

    ChainP P;
    P.c        = softplus_fast(curv);
    P.sc       = sqrt_fast(P.c);
    P.rcp_sc   = rcp_fast(P.sc);
    P.maxn_pre  = F_TANH_ARG_MAX * P.rcp_sc;
    P.maxn_post = F_BALL * P.rcp_sc;
    P.s        = rcp_fast(1.0f + exp_fast(-scent));      // sigmoid
    P.gamma    = (1.0f + softplus_fast(gscale)) * tanh_fast(graw);

    float4 xA[2][3], yA[2][3], xB[2][3], yB[2][3];

    int g = wglob;
    load_group(x, y, g, rows, lane, xA, yA);
    while (true) {
        const int gB = g + nwaves;
        if (gB < ngroups) {
            load_group(x, y, gB, rows, lane, xB, yB);       // prefetch B
            process_group(xA, yA, g, rows, lane, P, out);   // compute A
            const int gA = gB + nwaves;
            if (gA < ngroups) {
                load_group(x, y, gA, rows, lane, xA, yA);   // prefetch A
                process_group(xB, yB, gB, rows, lane, P, out);
                g = gA;
            } else {
                process_group(xB, yB, gB, rows, lane, P, out);
                return;
            }
        } else {
            process_group(xA, yA, g, rows, lane, P, out);
            return;
        }
    }
}

extern "C" void kernel_launch(void* const* d_in, const int* in_sizes, int n_in,
                              void* d_out, int out_size, void* d_ws, size_t ws_size,
                              hipStream_t stream) {
    const float* x = (const float*)d_in[0];
    const float* y = (const float*)d_in[1];
    const float* curv = (const float*)d_in[2];
    const float* graw = (const float*)d_in[3];
    const float* gscale = (const float*)d_in[4];
    const float* scent = (const float*)d_in[5];
    float* out = (float*)d_out;

    const int rows = in_sizes[0] / 768;          // 64*577 = 36928
    const int ngroups = (rows + 1) / 2;          // 2 rows per group
    // persistent-ish grid: ~4.5 groups per wave at full size
    int blocks = (ngroups + 3) / 4;              // upper bound: 1 group/wave min
    if (blocks > 1024) blocks = 1024;

    hipLaunchKernelGGL(hra_fused, dim3(blocks), dim3(256), 0, stream,
                       x, y, curv, graw, gscale, scent, out, rows);
}